// Round 3
// baseline (654.110 us; speedup 1.0000x reference)
//
#include <hip/hip_runtime.h>
#include <hip/hip_bf16.h>
#include <stddef.h>

// SpMM: out[r,:] = sum_{e: rows[e]==r} vals[e] * embeds[cols[e],:]
// N=100000 nodes, E=3200000 edges, D=128.
// Strategy: build CSR on-device (histogram -> scan -> scatter), then
// row-parallel gather with one wave (64 lanes) per output row.
// Each lane owns 2 contiguous floats of the row (float2), so the embeds
// gather is one coalesced dwordx2 per wave per edge (512B/row).

#define N_NODES_D 128

// ---------------- histogram ----------------
__global__ void hist_kernel(const int* __restrict__ rows, int* __restrict__ counts, int E) {
    int stride = gridDim.x * blockDim.x;
    for (int e = blockIdx.x * blockDim.x + threadIdx.x; e < E; e += stride) {
        atomicAdd(&counts[rows[e]], 1);
    }
}

// ---------------- 3-phase exclusive scan over counts[N] ----------------
__global__ void scan_blocks(const int* __restrict__ counts, int* __restrict__ offsets,
                            int* __restrict__ blocksums, int n) {
    __shared__ int tmp[1024];
    int t = threadIdx.x;
    int i = blockIdx.x * 1024 + t;
    int v = (i < n) ? counts[i] : 0;
    tmp[t] = v;
    __syncthreads();
    // Hillis-Steele inclusive scan
    for (int ofs = 1; ofs < 1024; ofs <<= 1) {
        int add = (t >= ofs) ? tmp[t - ofs] : 0;
        __syncthreads();
        tmp[t] += add;
        __syncthreads();
    }
    if (i < n) offsets[i] = tmp[t] - v;      // exclusive within block
    if (t == 1023) blocksums[blockIdx.x] = tmp[1023];
}

__global__ void scan_sums(int* __restrict__ blocksums, int nb) {
    __shared__ int tmp[128];
    int t = threadIdx.x;
    int v = (t < nb) ? blocksums[t] : 0;
    tmp[t] = v;
    __syncthreads();
    for (int ofs = 1; ofs < 128; ofs <<= 1) {
        int add = (t >= ofs) ? tmp[t - ofs] : 0;
        __syncthreads();
        tmp[t] += add;
        __syncthreads();
    }
    if (t < nb) blocksums[t] = tmp[t] - v;   // exclusive
}

__global__ void add_offsets(int* __restrict__ offsets, int* __restrict__ positions,
                            const int* __restrict__ blocksums, int n, int e_total) {
    int i = blockIdx.x * blockDim.x + threadIdx.x;
    if (i < n) {
        int o = offsets[i] + blocksums[i >> 10];
        offsets[i] = o;
        positions[i] = o;
    }
    if (i == 0) offsets[n] = e_total;
}

// ---------------- scatter edges into CSR order ----------------
__global__ void scatter_edges(const int* __restrict__ rows, const int* __restrict__ cols,
                              const float* __restrict__ vals, int* __restrict__ positions,
                              int2* __restrict__ pairs, int E) {
    int stride = gridDim.x * blockDim.x;
    for (int e = blockIdx.x * blockDim.x + threadIdx.x; e < E; e += stride) {
        int r = rows[e];
        int p = atomicAdd(&positions[r], 1);
        pairs[p] = make_int2(cols[e], __float_as_int(vals[e]));
    }
}

// ---------------- gather: one wave per row ----------------
__global__ __launch_bounds__(256) void gather_rows(const int* __restrict__ offsets,
                                                   const int2* __restrict__ pairs,
                                                   const float* __restrict__ embeds,
                                                   float* __restrict__ out, int N) {
    int gtid = blockIdx.x * blockDim.x + threadIdx.x;
    int wid = gtid >> 6;         // wave id == row id
    int lane = threadIdx.x & 63;
    if (wid >= N) return;

    int beg = offsets[wid];
    int end = offsets[wid + 1];

    float acc0 = 0.f, acc1 = 0.f;
    const float2* em2 = (const float2*)embeds;

    for (int base = beg; base < end; base += 64) {
        int idx = base + lane;
        int2 p = (idx < end) ? pairs[idx] : make_int2(0, 0);
        int lim = end - base;
        if (lim > 64) lim = 64;
        for (int j = 0; j < lim; ++j) {
            int c = __shfl(p.x, j);
            float v = __int_as_float(__shfl(p.y, j));
            float2 em = em2[(size_t)c * 64 + lane];
            acc0 = fmaf(v, em.x, acc0);
            acc1 = fmaf(v, em.y, acc1);
        }
    }
    ((float2*)out)[(size_t)wid * 64 + lane] = make_float2(acc0, acc1);
}

// ---------------- fallback: edge-parallel atomic scatter ----------------
__global__ void spmm_atomic(const int* __restrict__ rows, const int* __restrict__ cols,
                            const float* __restrict__ vals, const float* __restrict__ embeds,
                            float* __restrict__ out, int E) {
    int gtid = blockIdx.x * blockDim.x + threadIdx.x;
    int wid = gtid >> 6;
    int lane = threadIdx.x & 63;
    if (wid >= E) return;
    int r = rows[wid];
    int c = cols[wid];
    float v = vals[wid];
    float2 em = ((const float2*)embeds)[(size_t)c * 64 + lane];
    atomicAdd(&out[(size_t)r * 128 + lane * 2], v * em.x);
    atomicAdd(&out[(size_t)r * 128 + lane * 2 + 1], v * em.y);
}

extern "C" void kernel_launch(void* const* d_in, const int* in_sizes, int n_in,
                              void* d_out, int out_size, void* d_ws, size_t ws_size,
                              hipStream_t stream) {
    const float* embeds = (const float*)d_in[0];
    const int* edge_index = (const int*)d_in[1];
    const float* vals = (const float*)d_in[2];
    float* out = (float*)d_out;

    const int E = in_sizes[2];               // 3200000
    const int N = in_sizes[0] / N_NODES_D;   // 100000
    const int* rows = edge_index;            // edge_index[0, :]
    const int* cols = edge_index + E;        // edge_index[1, :]

    // workspace layout (16B-aligned chunks)
    size_t off = 0;
    auto take = [&](size_t bytes) {
        size_t cur = off;
        off += (bytes + 15) & ~(size_t)15;
        return cur;
    };
    char* ws = (char*)d_ws;
    size_t o_counts    = take((size_t)N * 4);
    size_t o_offsets   = take((size_t)(N + 1) * 4);
    size_t o_positions = take((size_t)N * 4);
    size_t o_blocksums = take(128 * 4);
    size_t o_pairs     = take((size_t)E * 8);
    size_t need = off;

    if (ws_size >= need) {
        int* counts    = (int*)(ws + o_counts);
        int* offsets   = (int*)(ws + o_offsets);
        int* positions = (int*)(ws + o_positions);
        int* blocksums = (int*)(ws + o_blocksums);
        int2* pairs    = (int2*)(ws + o_pairs);

        hipMemsetAsync(counts, 0, (size_t)N * 4, stream);

        hist_kernel<<<2048, 256, 0, stream>>>(rows, counts, E);

        int nb = (N + 1023) / 1024;          // 98
        scan_blocks<<<nb, 1024, 0, stream>>>(counts, offsets, blocksums, N);
        scan_sums<<<1, 128, 0, stream>>>(blocksums, nb);
        add_offsets<<<(N + 255) / 256, 256, 0, stream>>>(offsets, positions, blocksums, N, E);

        scatter_edges<<<2048, 256, 0, stream>>>(rows, cols, vals, positions, pairs, E);

        int waves = N;                        // one wave per row
        int blocks = (waves * 64 + 255) / 256;
        gather_rows<<<blocks, 256, 0, stream>>>(offsets, pairs, embeds, out, N);
    } else {
        // fallback: atomic scatter (needs no workspace)
        hipMemsetAsync(out, 0, (size_t)out_size * 4, stream);
        int waves = E;
        int blocks = (waves * 64 + 255) / 256;
        spmm_atomic<<<blocks, 256, 0, stream>>>(rows, cols, vals, embeds, out, E);
    }
}